// Round 5
// baseline (132.452 us; speedup 1.0000x reference)
//
#include <hip/hip_runtime.h>
#include <math.h>

#define LAYERS  8
#define FEAT    3072
#define NCLASS  10
#define DIM     4096
#define ST      66   // padded LDS row stride (floats)

typedef float v2f __attribute__((ext_vector_type(2)));
typedef float v4f __attribute__((ext_vector_type(4)));

__device__ __forceinline__ int px6c(int r) {
    int u = r ^ (r >> 1); u ^= u >> 2; u ^= u >> 4; return u;
}
__device__ __forceinline__ int gray6(int r) { return r ^ (r >> 1); }

// 6 in-register qubit butterflies over v[32] (reg bits 0..5 of r = 2i+comp).
// Reg bit p uses c = cl[off-p], s = sl[off-p]. Emits v_pk_* packed fp32.
__device__ __forceinline__ void butterflies6(v2f v[32],
                                             const float* __restrict__ cl,
                                             const float* __restrict__ sl,
                                             int off) {
    {
        const float c = cl[off], s = sl[off];
        const v2f c2 = {c, c};
        const v2f ms = {-s, s};
#pragma unroll
        for (int i = 0; i < 32; ++i) {
            v2f a = v[i];
            v2f sw = {a.y, a.x};
            v[i] = a * c2 + sw * ms;   // (c*x - s*y, s*x + c*y)
        }
    }
#pragma unroll
    for (int p = 1; p < 6; ++p) {
        const float c = cl[off - p], s = sl[off - p];
        const v2f c2 = {c, c};
        const v2f s2 = {s, s};
#pragma unroll
        for (int i0 = 0; i0 < 32; ++i0) {
            if (i0 & (1 << (p - 1))) continue;
            const int i1 = i0 | (1 << (p - 1));
            v2f a = v[i0], e = v[i1];
            v[i0] = a * c2 - e * s2;
            v[i1] = a * s2 + e * c2;
        }
    }
}

// A -> LDS: psi[64t+r] at f = t + ST*r (2-way banks = free; pairs mergeable to ds_write2)
__device__ __forceinline__ void storeA(const v2f v[32], float* __restrict__ L, int t) {
#pragma unroll
    for (int i = 0; i < 32; ++i) {
        float* p = L + t + ST * (2 * i);
        p[0]  = v[i].x;
        p[ST] = v[i].y;
    }
}

// LDS -> B: v[i] = (psi[64(2i)+t], psi[64(2i+1)+t]), b64, 2-way max
__device__ __forceinline__ void loadB(v2f v[32], const float* __restrict__ L, int t) {
#pragma unroll
    for (int i = 0; i < 32; ++i) {
        v[i] = *(const v2f*)(L + ST * t + 2 * i);
    }
}

// B -> LDS (own addresses, b64)
__device__ __forceinline__ void storeB(const v2f v[32], float* __restrict__ L, int t) {
#pragma unroll
    for (int i = 0; i < 32; ++i) {
        *(v2f*)(L + ST * t + 2 * i) = v[i];
    }
}

// LDS -> A with CNOT-cascade (Gray) perm folded: v[r] = psi[ginv(64t+r)]
__device__ __forceinline__ void loadGray(v2f v[32], const float* __restrict__ L,
                                         int base, int dsg) {
#pragma unroll
    for (int i = 0; i < 32; ++i) {
        const int k0 = ST * px6c(2 * i);          // compile-time constants
        const int k1 = ST * (px6c(2 * i) ^ 1);
        v2f nv;
        nv.x = L[base + dsg * k0];
        nv.y = L[base + dsg * k1];
        v[i] = nv;
    }
}

// epilogue scatter: q[g(j)] = psi[j]^2, B layout j = 64r+t,
// g(j) = 64*gray6(r) + (gray6(t) ^ ((r&1)<<5))
__device__ __forceinline__ void scatterProbs(const v2f v[32], float* __restrict__ L, int gt) {
#pragma unroll
    for (int i = 0; i < 32; ++i) {
        const int g0 = 64 * gray6(2 * i);
        const int g1 = 64 * (gray6(2 * i) ^ 1);
        L[g0 + gt]        = v[i].x * v[i].x;      // bank = gt&31: 2-way, free
        L[g1 + (gt ^ 32)] = v[i].y * v[i].y;
    }
}

__global__ __launch_bounds__(64, 1)
void qnn_kernel(const float* __restrict__ x,
                const float* __restrict__ ang,
                const float* __restrict__ W,
                const float* __restrict__ bias,
                float* __restrict__ out)
{
    __shared__ float lds0[ST * 64];     // 16896 B, state 0
    __shared__ float lds1[ST * 64];     // 16896 B, state 1
    __shared__ float cst[96], snt[96];

    const int t  = threadIdx.x;         // 0..63, single wave per block
    const int b0 = 2 * blockIdx.x;      // two states per wave
    const int b1 = b0 + 1;

    // ---- trig tables (96 angles); single wave -> no barrier needed anywhere ----
    {
        float a0 = ang[t];
        cst[t] = cosf(a0);
        snt[t] = sinf(a0);
        if (t < 32) {
            float a1 = ang[64 + t];
            cst[64 + t] = cosf(a1);
            snt[64 + t] = sinf(a1);
        }
    }

    // ---- load both states, A layout: v[i] = (psi[64t+2i], psi[64t+2i+1]) ----
    v2f va[32], vb[32];
    {
        const float* xr0 = x + (size_t)b0 * FEAT + 64 * t;
        const float* xr1 = x + (size_t)b1 * FEAT + 64 * t;
        if (t < FEAT / 64) {            // t < 48: real features
#pragma unroll
            for (int j = 0; j < 16; ++j) {
                v4f f0 = *(const v4f*)(xr0 + 4 * j);
                v4f f1 = *(const v4f*)(xr1 + 4 * j);
                va[2 * j]     = (v2f){f0.x, f0.y};
                va[2 * j + 1] = (v2f){f0.z, f0.w};
                vb[2 * j]     = (v2f){f1.x, f1.y};
                vb[2 * j + 1] = (v2f){f1.z, f1.w};
            }
        } else {
#pragma unroll
            for (int i = 0; i < 32; ++i) { va[i] = (v2f){0.f, 0.f}; vb[i] = (v2f){0.f, 0.f}; }
        }
    }

    // ---- ||x||^2 for both (normalization deferred: circuit is linear) ----
    float inv0, inv1;
    {
        v2f sa = {0.f, 0.f}, sb = {0.f, 0.f};
#pragma unroll
        for (int i = 0; i < 32; ++i) { sa += va[i] * va[i]; sb += vb[i] * vb[i]; }
        float s0 = sa.x + sa.y, s1 = sb.x + sb.y;
#pragma unroll
        for (int o = 1; o < 64; o <<= 1) {
            s0 += __shfl_xor(s0, o, 64);
            s1 += __shfl_xor(s1, o, 64);
        }
        inv0 = 1.0f / s0;
        inv1 = 1.0f / s1;
    }

    // Gray-read helpers
    int px = t ^ (t >> 1); px ^= px >> 2; px ^= px >> 4;   // px6(t)
    const int flip = px & 1;
    const int base = px + (flip ? ST * 63 : 0);            // K^63 = 63-K trick
    const int dsg  = flip ? -1 : 1;

#pragma unroll 1
    for (int l = 0; l < LAYERS; ++l) {
        const float* cl = cst + l * 12;
        const float* sl = snt + l * 12;

        butterflies6(va, cl, sl, 11);
        butterflies6(vb, cl, sl, 11);

        storeA(va, lds0, t);
        storeA(vb, lds1, t);
        loadB(va, lds0, t);
        loadB(vb, lds1, t);

        butterflies6(va, cl, sl, 5);
        butterflies6(vb, cl, sl, 5);

        if (l == LAYERS - 1) break;     // last layer: Gray folds into epilogue

        storeB(va, lds0, t);
        storeB(vb, lds1, t);
        loadGray(va, lds0, base, dsg);
        loadGray(vb, lds1, base, dsg);
    }

    // ---- epilogue: scatter Gray-permuted probs, then shared-W dot products ----
    const int gt = gray6(t);
    scatterProbs(va, lds0, gt);
    scatterProbs(vb, lds1, gt);

    float acc0[NCLASS], acc1[NCLASS];
#pragma unroll
    for (int c = 0; c < NCLASS; ++c) { acc0[c] = 0.f; acc1[c] = 0.f; }

#pragma unroll 1
    for (int k = 0; k < 16; ++k) {
        const v4f q0 = *(const v4f*)(lds0 + 4 * t + 256 * k);   // b128, conflict-free
        const v4f q1 = *(const v4f*)(lds1 + 4 * t + 256 * k);
        const float* wp = W + 4 * t + 256 * k;
#pragma unroll
        for (int c = 0; c < NCLASS; ++c) {
            const v4f w4 = *(const v4f*)(wp + c * DIM);          // shared by both states
            acc0[c] += q0.x * w4.x + q0.y * w4.y + q0.z * w4.z + q0.w * w4.w;
            acc1[c] += q1.x * w4.x + q1.y * w4.y + q1.z * w4.z + q1.w * w4.w;
        }
    }

#pragma unroll
    for (int c = 0; c < NCLASS; ++c) {
        float a0 = acc0[c], a1 = acc1[c];
#pragma unroll
        for (int o = 1; o < 64; o <<= 1) {
            a0 += __shfl_xor(a0, o, 64);
            a1 += __shfl_xor(a1, o, 64);
        }
        if (t == 0) {
            out[b0 * NCLASS + c] = fmaf(a0, inv0, bias[c]);
            out[b1 * NCLASS + c] = fmaf(a1, inv1, bias[c]);
        }
    }
}

extern "C" void kernel_launch(void* const* d_in, const int* in_sizes, int n_in,
                              void* d_out, int out_size, void* d_ws, size_t ws_size,
                              hipStream_t stream) {
    const float* x    = (const float*)d_in[0];
    const float* ang  = (const float*)d_in[1];
    const float* W    = (const float*)d_in[2];
    const float* bias = (const float*)d_in[3];
    float* out = (float*)d_out;
    const int batch = in_sizes[0] / FEAT;   // 2048
    qnn_kernel<<<batch / 2, 64, 0, stream>>>(x, ang, W, bias, out);
}

// Round 6
// 119.971 us; speedup vs baseline: 1.1040x; 1.1040x over previous
//
#include <hip/hip_runtime.h>
#include <math.h>

#define LAYERS  8
#define FEAT    3072
#define NCLASS  10
#define DIM     4096
#define ST      66   // padded LDS row stride (floats)

typedef float v2f __attribute__((ext_vector_type(2)));
typedef float v4f __attribute__((ext_vector_type(4)));

// prefix-xor (inverse Gray) of 6-bit value; compile-time under unroll
__device__ __forceinline__ int px6c(int r) {
    int u = r ^ (r >> 1); u ^= u >> 2; u ^= u >> 4; return u & 63;
}
__device__ __forceinline__ int gray6(int r) { return (r ^ (r >> 1)) & 63; }

__device__ __forceinline__ float getc(const v2f v[32], int u) {
    return (u & 1) ? v[u >> 1].y : v[u >> 1].x;
}
__device__ __forceinline__ void setc(v2f v[32], int u, float x) {
    if (u & 1) v[u >> 1].y = x; else v[u >> 1].x = x;
}
__device__ __forceinline__ float bpermf(int addr, float x) {
    return __int_as_float(__builtin_amdgcn_ds_bpermute(addr, __float_as_int(x)));
}

// 6 register-qubit butterflies over v[32] (index bits 0..5 of r = 2i+comp in the
// current layout's register dimension). Reg bit p uses cl[off-p]/sl[off-p].
__device__ __forceinline__ void butterflies6(v2f v[32],
                                             const float* __restrict__ cl,
                                             const float* __restrict__ sl,
                                             int off) {
    {
        const float c = cl[off], s = sl[off];
        const v2f c2 = {c, c};
        const v2f ms = {-s, s};
#pragma unroll
        for (int i = 0; i < 32; ++i) {
            v2f a = v[i];
            v2f sw = {a.y, a.x};
            v[i] = a * c2 + sw * ms;   // (c*x - s*y, s*x + c*y)
        }
    }
#pragma unroll
    for (int p = 1; p < 6; ++p) {
        const float c = cl[off - p], s = sl[off - p];
        const v2f c2 = {c, c};
        const v2f s2 = {s, s};
#pragma unroll
        for (int i0 = 0; i0 < 32; ++i0) {
            if (i0 & (1 << (p - 1))) continue;
            const int i1 = i0 | (1 << (p - 1));
            v2f a = v[i0], e = v[i1];
            v[i0] = a * c2 - e * s2;
            v[i1] = a * s2 + e * c2;
        }
    }
}

__global__ __launch_bounds__(64)
void qnn_kernel(const float* __restrict__ x,
                const float* __restrict__ ang,
                const float* __restrict__ W,
                const float* __restrict__ bias,
                float* __restrict__ out)
{
    __shared__ float lds[ST * 64];      // 16896 B; reused for q[] in epilogue
    __shared__ float cst[96], snt[96];

    const int t = threadIdx.x;          // 0..63, single wave per block/state
    const int b = blockIdx.x;

    // ---- trig tables (96 angles); single wave, in-order DS -> no barrier ----
    {
        float a0 = ang[t];
        cst[t] = cosf(a0);
        snt[t] = sinf(a0);
        if (t < 32) {
            float a1 = ang[64 + t];
            cst[64 + t] = cosf(a1);
            snt[64 + t] = sinf(a1);
        }
    }

    // ---- load psi0 directly in B layout: v[r] = psi[64r + t] (coalesced b32) ----
    v2f v[32];
    {
        const float* xb = x + (size_t)b * FEAT;
#pragma unroll
        for (int r = 0; r < 64; ++r) {
            if (r < FEAT / 64) setc(v, r, xb[64 * r + t]);
            else               setc(v, r, 0.f);
        }
    }

    // ---- ||x||^2 (normalization deferred: circuit is linear) ----
    float invn2;
    {
        v2f s2 = {0.f, 0.f};
#pragma unroll
        for (int i = 0; i < 32; ++i) s2 += v[i] * v[i];
        float ss = s2.x + s2.y;
#pragma unroll
        for (int o = 1; o < 64; o <<= 1) ss += __shfl_xor(ss, o, 64);
        invn2 = 1.0f / ss;
    }

    // ---- bpermute address registers for the Gray lane-permutation ----
    int px = t ^ (t >> 1); px ^= px >> 2; px ^= px >> 4; px &= 63;  // px6(t)
    const int A0 = 4 * px;
    const int A1 = 4 * (px ^ 63);
    const bool oddlane = (t & 1);

#pragma unroll 1
    for (int p = 0; p < 4; ++p) {
        // ================= even layer l = 2p: starts in B layout =================
        {
            const float* cl = cst + (2 * p) * 12;
            const float* sl = snt + (2 * p) * 12;

            butterflies6(v, cl, sl, 5);          // qubits 5..0 (regs = index hi bits)

            // transpose B->A: store own rows b64, read columns b32 (round-3 patterns)
#pragma unroll
            for (int i = 0; i < 32; ++i)
                *(v2f*)(lds + ST * t + 2 * i) = v[i];
#pragma unroll
            for (int u = 0; u < 64; ++u)
                setc(v, u, lds[t + ST * u]);

            butterflies6(v, cl, sl, 11);         // qubits 11..6 (regs = index lo bits)

            // Gray in A layout: w[sigma] = old[sigma ^ 63*lsb(lane)], then
            // new[rho] = bperm(A0, w[px6(rho)])
            {
                float w[64];
#pragma unroll
                for (int s = 0; s < 32; ++s) {
                    const float a = getc(v, s);
                    const float c = getc(v, 63 - s);        // s ^ 63
                    w[s]      = oddlane ? c : a;
                    w[63 - s] = oddlane ? a : c;
                }
#pragma unroll
                for (int r = 0; r < 64; ++r)
                    setc(v, r, bpermf(A0, w[px6c(r)]));
            }
        }

        // ================= odd layer l = 2p+1: starts in A layout ================
        {
            const float* cl = cst + (2 * p + 1) * 12;
            const float* sl = snt + (2 * p + 1) * 12;

            butterflies6(v, cl, sl, 11);         // qubits 11..6 (regs = index lo bits)

            // transpose A->B: store columns b32, read own rows b64
#pragma unroll
            for (int u = 0; u < 64; ++u)
                lds[t + ST * u] = getc(v, u);
#pragma unroll
            for (int i = 0; i < 32; ++i)
                v[i] = *(const v2f*)(lds + ST * t + 2 * i);

            butterflies6(v, cl, sl, 5);          // qubits 5..0 (regs = index hi bits)

            if (p < 3) {
                // Gray in B layout: new[rho] = bperm(parity(rho)?A1:A0, old[px6(rho)])
                float n[64];
#pragma unroll
                for (int r = 0; r < 64; ++r) {
                    const int srcr = px6c(r);               // compile-time
                    n[r] = bpermf((srcr & 1) ? A1 : A0, getc(v, srcr));
                }
#pragma unroll
                for (int r = 0; r < 64; ++r)
                    setc(v, r, n[r]);
            }
            // l == 7: final Gray folds into the epilogue scatter
        }
    }

    // ---- epilogue (B layout, Gray(7) folded): q[g(j)] = psi[j]^2,
    //      j = 64r + t, g(j) = 64*gray6(r) + (gray6(t) ^ 32*(r&1)) ----
    const int gt = gray6(t);
#pragma unroll
    for (int i = 0; i < 32; ++i) {
        const int g0 = 64 * gray6(2 * i);
        const int g1 = 64 * (gray6(2 * i) ^ 1);
        lds[g0 + gt]        = v[i].x * v[i].x;   // bank = gt&31: 2-way, free
        lds[g1 + (gt ^ 32)] = v[i].y * v[i].y;
    }

    float acc[NCLASS];
#pragma unroll
    for (int c = 0; c < NCLASS; ++c) acc[c] = 0.f;

#pragma unroll 1
    for (int k = 0; k < 16; ++k) {
        const v4f q4 = *(const v4f*)(lds + 4 * t + 256 * k);   // b128, conflict-free
        const float* wp = W + 4 * t + 256 * k;
#pragma unroll
        for (int c = 0; c < NCLASS; ++c) {
            const v4f w4 = *(const v4f*)(wp + c * DIM);         // dwordx4, L2-resident
            acc[c] += q4.x * w4.x + q4.y * w4.y + q4.z * w4.z + q4.w * w4.w;
        }
    }

#pragma unroll
    for (int c = 0; c < NCLASS; ++c) {
        float a = acc[c];
#pragma unroll
        for (int o = 1; o < 64; o <<= 1) a += __shfl_xor(a, o, 64);
        if (t == 0) out[b * NCLASS + c] = fmaf(a, invn2, bias[c]);
    }
}

extern "C" void kernel_launch(void* const* d_in, const int* in_sizes, int n_in,
                              void* d_out, int out_size, void* d_ws, size_t ws_size,
                              hipStream_t stream) {
    const float* x    = (const float*)d_in[0];
    const float* ang  = (const float*)d_in[1];
    const float* W    = (const float*)d_in[2];
    const float* bias = (const float*)d_in[3];
    float* out = (float*)d_out;
    const int batch = in_sizes[0] / FEAT;   // 2048
    qnn_kernel<<<batch, 64, 0, stream>>>(x, ang, W, bias, out);
}

// Round 7
// 117.986 us; speedup vs baseline: 1.1226x; 1.0168x over previous
//
#include <hip/hip_runtime.h>
#include <math.h>

#define LAYERS  8
#define FEAT    3072
#define NCLASS  10
#define DIM     4096
#define ST      66   // padded LDS row stride (floats)

typedef float v2f __attribute__((ext_vector_type(2)));
typedef float v4f __attribute__((ext_vector_type(4)));

// prefix-xor (inverse Gray) of 6-bit value; compile-time under unroll
__device__ __forceinline__ int px6c(int r) {
    int u = r ^ (r >> 1); u ^= u >> 2; u ^= u >> 4; return u & 63;
}
__device__ __forceinline__ int gray6(int r) { return (r ^ (r >> 1)) & 63; }

__device__ __forceinline__ float getc(const v2f v[32], int u) {
    return (u & 1) ? v[u >> 1].y : v[u >> 1].x;
}
__device__ __forceinline__ void setc(v2f v[32], int u, float x) {
    if (u & 1) v[u >> 1].y = x; else v[u >> 1].x = x;
}
__device__ __forceinline__ float bpermf(int addr, float x) {
    return __int_as_float(__builtin_amdgcn_ds_bpermute(addr, __float_as_int(x)));
}

// plain 6 register-qubit butterflies (packed v2f); reg bit p uses cl[off-p]/sl[off-p]
__device__ __forceinline__ void butterflies6(v2f v[32],
                                             const float* __restrict__ cl,
                                             const float* __restrict__ sl,
                                             int off) {
    {
        const float c = cl[off], s = sl[off];
        const v2f c2 = {c, c};
        const v2f ms = {-s, s};
#pragma unroll
        for (int i = 0; i < 32; ++i) {
            v2f a = v[i];
            v2f sw = {a.y, a.x};
            v[i] = a * c2 + sw * ms;   // (c*x - s*y, s*x + c*y)
        }
    }
#pragma unroll
    for (int p = 1; p < 6; ++p) {
        const float c = cl[off - p], s = sl[off - p];
        const v2f c2 = {c, c};
        const v2f s2 = {s, s};
#pragma unroll
        for (int i0 = 0; i0 < 32; ++i0) {
            if (i0 & (1 << (p - 1))) continue;
            const int i1 = i0 | (1 << (p - 1));
            v2f a = v[i0], e = v[i1];
            v[i0] = a * c2 - e * s2;
            v[i1] = a * s2 + e * c2;
        }
    }
}

// A-phase CONJUGATED by the deferred GrayA (ginv renaming, GF(2)-linear):
// new-bit b butterfly -> old-reg pairs {s, s^(2^(b+1)-1)}; orientation sign
// compile-time from s_{b+1}, except b=5 where it is parity(lane) (snl).
__device__ __forceinline__ void butterflies6_renamed(v2f v[32],
                                                     const float* __restrict__ cl,
                                                     const float* __restrict__ sl,
                                                     float parity_sign) {
    // b = 0: pairs {2k, 2k+1} inside each v2f; sign from k&1 (= s_1)
    {
        const float c = cl[11], s = sl[11];
        const v2f c2 = {c, c};
#pragma unroll
        for (int k = 0; k < 32; ++k) {
            const float sg = (k & 1) ? -s : s;
            v2f a = v[k];
            v2f sw = {a.y, a.x};
            v2f ms = {-sg, sg};
            v[k] = a * c2 + sw * ms;
        }
    }
    // b = 1..4: scattered pairs, scalar; sign from s_{b+1}
#pragma unroll
    for (int b = 1; b < 5; ++b) {
        const float c = cl[11 - b], s = sl[11 - b];
#pragma unroll
        for (int s0 = 0; s0 < 64; ++s0) {
            if (s0 & (1 << b)) continue;               // canonical: bit b == 0
            const int s1 = s0 ^ ((2 << b) - 1);        // partner: ^ prefix mask
            const float sg = (s0 & (2 << b)) ? -s : s; // s_{b+1}
            const float a = getc(v, s0), e = getc(v, s1);
            setc(v, s0, c * a - sg * e);
            setc(v, s1, sg * a + c * e);
        }
    }
    // b = 5: pairs {s, 63-s}; per-lane sign snl = parity(lane) ? -s : s
    {
        const float c = cl[6];
        const float snl = parity_sign * sl[6];
#pragma unroll
        for (int s0 = 0; s0 < 32; ++s0) {
            const int s1 = 63 - s0;
            const float a = getc(v, s0), e = getc(v, s1);
            setc(v, s0, c * a - snl * e);
            setc(v, s1, snl * a + c * e);
        }
    }
}

__global__ __launch_bounds__(64)
void qnn_kernel(const float* __restrict__ x,
                const float* __restrict__ ang,
                const float* __restrict__ W,
                const float* __restrict__ bias,
                float* __restrict__ out)
{
    __shared__ float lds[ST * 64];      // 16896 B; reused for q[] in epilogue
    __shared__ float cst[96], snt[96];

    const int t = threadIdx.x;          // 0..63, single wave per block/state
    const int b = blockIdx.x;

    // ---- trig tables (96 angles); single wave, in-order DS -> no barrier ----
    {
        float a0 = ang[t];
        cst[t] = cosf(a0);
        snt[t] = sinf(a0);
        if (t < 32) {
            float a1 = ang[64 + t];
            cst[64 + t] = cosf(a1);
            snt[64 + t] = sinf(a1);
        }
    }

    // ---- load psi0 directly in B layout: v[r] = psi[64r + t] (coalesced b32) ----
    v2f v[32];
    {
        const float* xb = x + (size_t)b * FEAT;
#pragma unroll
        for (int r = 0; r < 64; ++r) {
            if (r < FEAT / 64) setc(v, r, xb[64 * r + t]);
            else               setc(v, r, 0.f);
        }
    }

    // ---- ||x||^2 (normalization deferred: circuit is linear) ----
    float invn2;
    {
        v2f s2 = {0.f, 0.f};
#pragma unroll
        for (int i = 0; i < 32; ++i) s2 += v[i] * v[i];
        float ss = s2.x + s2.y;
#pragma unroll
        for (int o = 1; o < 64; o <<= 1) ss += __shfl_xor(ss, o, 64);
        invn2 = 1.0f / ss;
    }

    // ---- per-lane constants ----
    int px = t ^ (t >> 1); px ^= px >> 2; px ^= px >> 4; px &= 63;  // px6(t)
    const int A0 = 4 * px;                    // bpermute byte addrs (GrayB)
    const int A1 = 4 * (px ^ 63);
    const int u0 = t & 1;
    const float psgn = u0 ? -1.f : 1.f;       // parity sign for renamed b=5
    const int gtl = gray6(t);
    const int bp  = gtl + 32 * ST * u0;       // folded-GrayA store bases
    const int bm  = gtl - 32 * ST * u0;

    // ---- layer 0 (even, clean): B-phase, transpose B->A, A-phase ----
    {
        const float* cl = cst;
        const float* sl = snt;
        butterflies6(v, cl, sl, 5);                   // qubits 5..0 (reg = hi bits)
#pragma unroll
        for (int i = 0; i < 32; ++i)                  // write own rows (b64)
            *(v2f*)(lds + ST * t + 2 * i) = v[i];
#pragma unroll
        for (int u = 0; u < 64; ++u)                  // read columns (b32)
            setc(v, u, lds[t + ST * u]);
        butterflies6(v, cl, sl, 11);                  // qubits 11..6 (reg = lo bits)
        // GrayA(0): deferred into layer 1
    }

#pragma unroll 1
    for (int p = 0; p < 4; ++p) {
        // ======== odd layer 2p+1: renamed A-phase, folded transpose, B-phase ========
        {
            const float* cl = cst + (2 * p + 1) * 12;
            const float* sl = snt + (2 * p + 1) * 12;

            butterflies6_renamed(v, cl, sl, psgn);

            // transpose A->B with GrayA folded into store addresses:
            // element (lane t, reg s) -> addr = ((gray6(s)&32)? bm : bp) + ST*gray6(s)
#pragma unroll
            for (int s = 0; s < 64; ++s) {
                const int g = gray6(s);                       // compile-time
                lds[((g & 32) ? bm : bp) + ST * g] = getc(v, s);
            }
#pragma unroll
            for (int i = 0; i < 32; ++i)                      // read own rows (b64)
                v[i] = *(const v2f*)(lds + ST * t + 2 * i);

            butterflies6(v, cl, sl, 5);                       // qubits 5..0

            if (p < 3) {
                // GrayB (eager): new[r] = bperm(parity(src)?A1:A0, old[px6(r)])
                float n[64];
#pragma unroll
                for (int r = 0; r < 64; ++r) {
                    const int srcr = px6c(r);                 // compile-time
                    n[r] = bpermf((srcr & 1) ? A1 : A0, getc(v, srcr));
                }
#pragma unroll
                for (int r = 0; r < 64; ++r)
                    setc(v, r, n[r]);
            }
            // p == 3 (layer 7): final Gray folds into the epilogue scatter
        }

        if (p == 3) break;

        // ======== even layer 2p+2 (clean): B-phase, transpose B->A, A-phase ========
        {
            const float* cl = cst + (2 * p + 2) * 12;
            const float* sl = snt + (2 * p + 2) * 12;

            butterflies6(v, cl, sl, 5);
#pragma unroll
            for (int i = 0; i < 32; ++i)
                *(v2f*)(lds + ST * t + 2 * i) = v[i];
#pragma unroll
            for (int u = 0; u < 64; ++u)
                setc(v, u, lds[t + ST * u]);
            butterflies6(v, cl, sl, 11);
            // GrayA: deferred into next odd layer
        }
    }

    // ---- epilogue (B layout, Gray(7) folded): q[g(j)] = psi[j]^2,
    //      j = 64r + t, g(j) = 64*gray6(r) + (gray6(t) ^ 32*(r&1)) ----
#pragma unroll
    for (int i = 0; i < 32; ++i) {
        const int g0 = 64 * gray6(2 * i);
        const int g1 = 64 * (gray6(2 * i) ^ 1);
        lds[g0 + gtl]        = v[i].x * v[i].x;   // bank = gtl&31: 2-way, free
        lds[g1 + (gtl ^ 32)] = v[i].y * v[i].y;
    }

    float acc[NCLASS];
#pragma unroll
    for (int c = 0; c < NCLASS; ++c) acc[c] = 0.f;

#pragma unroll 1
    for (int k = 0; k < 16; ++k) {
        const v4f q4 = *(const v4f*)(lds + 4 * t + 256 * k);   // b128, conflict-free
        const float* wp = W + 4 * t + 256 * k;
#pragma unroll
        for (int c = 0; c < NCLASS; ++c) {
            const v4f w4 = *(const v4f*)(wp + c * DIM);         // dwordx4, L2-resident
            acc[c] += q4.x * w4.x + q4.y * w4.y + q4.z * w4.z + q4.w * w4.w;
        }
    }

#pragma unroll
    for (int c = 0; c < NCLASS; ++c) {
        float a = acc[c];
#pragma unroll
        for (int o = 1; o < 64; o <<= 1) a += __shfl_xor(a, o, 64);
        if (t == 0) out[b * NCLASS + c] = fmaf(a, invn2, bias[c]);
    }
}

extern "C" void kernel_launch(void* const* d_in, const int* in_sizes, int n_in,
                              void* d_out, int out_size, void* d_ws, size_t ws_size,
                              hipStream_t stream) {
    const float* x    = (const float*)d_in[0];
    const float* ang  = (const float*)d_in[1];
    const float* W    = (const float*)d_in[2];
    const float* bias = (const float*)d_in[3];
    float* out = (float*)d_out;
    const int batch = in_sizes[0] / FEAT;   // 2048
    qnn_kernel<<<batch, 64, 0, stream>>>(x, ang, W, bias, out);
}

// Round 8
// 114.000 us; speedup vs baseline: 1.1619x; 1.0350x over previous
//
#include <hip/hip_runtime.h>
#include <math.h>

#define LAYERS  8
#define FEAT    3072
#define NCLASS  10
#define DIM     4096
#define ST      66   // padded LDS row stride (floats)

typedef float v2f __attribute__((ext_vector_type(2)));
typedef float v4f __attribute__((ext_vector_type(4)));

// prefix-xor (inverse Gray) of 6-bit value; compile-time under unroll
__device__ __forceinline__ int px6c(int r) {
    int u = r ^ (r >> 1); u ^= u >> 2; u ^= u >> 4; return u & 63;
}
__device__ __forceinline__ int gray6(int r) { return (r ^ (r >> 1)) & 63; }

__device__ __forceinline__ float getc(const v2f v[32], int u) {
    return (u & 1) ? v[u >> 1].y : v[u >> 1].x;
}
__device__ __forceinline__ void setc(v2f v[32], int u, float x) {
    if (u & 1) v[u >> 1].y = x; else v[u >> 1].x = x;
}
__device__ __forceinline__ float bpermf(int addr, float x) {
    return __int_as_float(__builtin_amdgcn_ds_bpermute(addr, __float_as_int(x)));
}

// plain 6 register-qubit butterflies (packed v2f); reg bit p uses cl[off-p]/sl[off-p]
__device__ __forceinline__ void butterflies6(v2f v[32],
                                             const float* __restrict__ cl,
                                             const float* __restrict__ sl,
                                             int off) {
    {
        const float c = cl[off], s = sl[off];
        const v2f c2 = {c, c};
        const v2f ms = {-s, s};
#pragma unroll
        for (int i = 0; i < 32; ++i) {
            v2f a = v[i];
            v2f sw = {a.y, a.x};
            v[i] = a * c2 + sw * ms;   // (c*x - s*y, s*x + c*y)
        }
    }
#pragma unroll
    for (int p = 1; p < 6; ++p) {
        const float c = cl[off - p], s = sl[off - p];
        const v2f c2 = {c, c};
        const v2f s2 = {s, s};
#pragma unroll
        for (int i0 = 0; i0 < 32; ++i0) {
            if (i0 & (1 << (p - 1))) continue;
            const int i1 = i0 | (1 << (p - 1));
            v2f a = v[i0], e = v[i1];
            v[i0] = a * c2 - e * s2;
            v[i1] = a * s2 + e * c2;
        }
    }
}

// A-phase CONJUGATED by the deferred GrayA — PACKED form.
// New-bit b butterfly -> old pairs {s, s^(2^{b+1}-1)} (odd masks): v2f pairing
// m <-> swap(v2f[m ^ (2^b - 1)]), canonical bit_{b-1}(m)==0, uniform sign
// sg = bit_b(m) ? -s : +s (compile-time); b=5 sign is per-lane parity (snl).
__device__ __forceinline__ void butterflies6_renamed(v2f v[32],
                                                     const float* __restrict__ cl,
                                                     const float* __restrict__ sl,
                                                     float psgn) {
    // b = 0: pairs {2k,2k+1} inside each v2f; sign from k&1
    {
        const float c = cl[11], s = sl[11];
        const v2f c2 = {c, c};
        const v2f msA = {-s, s};      // k even: sg=+s
        const v2f msB = {s, -s};      // k odd:  sg=-s
#pragma unroll
        for (int k = 0; k < 32; ++k) {
            v2f a = v[k];
            v2f sw = {a.y, a.x};
            v[k] = a * c2 + sw * ((k & 1) ? msB : msA);
        }
    }
    // b = 1..4: packed cross-v2f with swapped partner
#pragma unroll
    for (int b = 1; b < 5; ++b) {
        const float c = cl[11 - b], s = sl[11 - b];
        const v2f c2 = {c, c};
#pragma unroll
        for (int m = 0; m < 32; ++m) {
            if (m & (1 << (b - 1))) continue;          // canonical side
            const int part = m ^ ((1 << b) - 1);
            const float sg = (m & (1 << b)) ? -s : s;  // compile-time
            const v2f sg2 = {sg, sg};
            const v2f A = v[m], E = v[part];
            const v2f Esw = {E.y, E.x};
            const v2f Asw = {A.y, A.x};
            v[m]    = A * c2 - Esw * sg2;
            v[part] = Asw * sg2 + E * c2;
        }
    }
    // b = 5: pairs m <-> m^31 (m < 16), per-lane sign snl
    {
        const float c = cl[6];
        const float snl = psgn * sl[6];
        const v2f c2 = {c, c};
        const v2f sg2 = {snl, snl};
#pragma unroll
        for (int m = 0; m < 16; ++m) {
            const int part = m ^ 31;
            const v2f A = v[m], E = v[part];
            const v2f Esw = {E.y, E.x};
            const v2f Asw = {A.y, A.x};
            v[m]    = A * c2 - Esw * sg2;
            v[part] = Asw * sg2 + E * c2;
        }
    }
}

__global__ __launch_bounds__(64)
void qnn_kernel(const float* __restrict__ x,
                const float* __restrict__ ang,
                const float* __restrict__ W,
                const float* __restrict__ bias,
                float* __restrict__ out)
{
    __shared__ float lds[ST * 64];      // 16896 B; reused for q[] in epilogue
    __shared__ float cst[96], snt[96];

    const int t = threadIdx.x;          // 0..63, single wave per block/state
    const int b = blockIdx.x;

    // ---- trig tables (96 angles); single wave, in-order DS -> no barrier ----
    {
        float a0 = ang[t];
        cst[t] = cosf(a0);
        snt[t] = sinf(a0);
        if (t < 32) {
            float a1 = ang[64 + t];
            cst[64 + t] = cosf(a1);
            snt[64 + t] = sinf(a1);
        }
    }

    // ---- load psi0 directly in B layout: v[r] = psi[64r + t] (coalesced b32) ----
    v2f v[32];
    {
        const float* xb = x + (size_t)b * FEAT;
#pragma unroll
        for (int r = 0; r < 64; ++r) {
            if (r < FEAT / 64) setc(v, r, xb[64 * r + t]);
            else               setc(v, r, 0.f);
        }
    }

    // ---- ||x||^2 (normalization deferred: circuit is linear) ----
    float invn2;
    {
        v2f s2 = {0.f, 0.f};
#pragma unroll
        for (int i = 0; i < 32; ++i) s2 += v[i] * v[i];
        float ss = s2.x + s2.y;
#pragma unroll
        for (int o = 1; o < 64; o <<= 1) ss += __shfl_xor(ss, o, 64);
        invn2 = 1.0f / ss;
    }

    // ---- per-lane constants ----
    int px = t ^ (t >> 1); px ^= px >> 2; px ^= px >> 4; px &= 63;  // px6(t)
    const int A0 = 4 * px;                    // bpermute byte addrs (GrayB)
    const int A1 = 4 * (px ^ 63);
    const int u0 = t & 1;
    const float psgn = u0 ? -1.f : 1.f;       // parity sign for renamed b=5
    const int gtl = gray6(t);
    const int bp  = gtl + 32 * ST * u0;       // folded-GrayA store bases
    const int bm  = gtl - 32 * ST * u0;

    // ---- layer 0 (even, clean): B-phase, transpose B->A, A-phase ----
    {
        const float* cl = cst;
        const float* sl = snt;
        butterflies6(v, cl, sl, 5);                   // qubits 5..0 (reg = hi bits)
#pragma unroll
        for (int i = 0; i < 32; ++i)                  // write own rows (b64)
            *(v2f*)(lds + ST * t + 2 * i) = v[i];
#pragma unroll
        for (int u = 0; u < 64; ++u)                  // read columns (b32)
            setc(v, u, lds[t + ST * u]);
        butterflies6(v, cl, sl, 11);                  // qubits 11..6 (reg = lo bits)
        // GrayA(0): deferred into layer 1
    }

#pragma unroll 1
    for (int p = 0; p < 4; ++p) {
        // ======== odd layer 2p+1: renamed A-phase, folded transpose, B-phase ========
        {
            const float* cl = cst + (2 * p + 1) * 12;
            const float* sl = snt + (2 * p + 1) * 12;

            butterflies6_renamed(v, cl, sl, psgn);

            // transpose A->B with GrayA folded into store addresses:
            // element (lane t, reg s) -> addr = ((gray6(s)&32)? bm : bp) + ST*gray6(s)
#pragma unroll
            for (int s = 0; s < 64; ++s) {
                const int g = gray6(s);                       // compile-time
                lds[((g & 32) ? bm : bp) + ST * g] = getc(v, s);
            }
#pragma unroll
            for (int i = 0; i < 32; ++i)                      // read own rows (b64)
                v[i] = *(const v2f*)(lds + ST * t + 2 * i);

            butterflies6(v, cl, sl, 5);                       // qubits 5..0

            if (p < 3) {
                // GrayB (eager): new[r] = bperm(parity(src)?A1:A0, old[px6(r)])
                float n[64];
#pragma unroll
                for (int r = 0; r < 64; ++r) {
                    const int srcr = px6c(r);                 // compile-time
                    n[r] = bpermf((srcr & 1) ? A1 : A0, getc(v, srcr));
                }
#pragma unroll
                for (int r = 0; r < 64; ++r)
                    setc(v, r, n[r]);
            }
            // p == 3 (layer 7): final Gray folds into the epilogue scatter
        }

        if (p == 3) break;

        // ======== even layer 2p+2 (clean): B-phase, transpose B->A, A-phase ========
        {
            const float* cl = cst + (2 * p + 2) * 12;
            const float* sl = snt + (2 * p + 2) * 12;

            butterflies6(v, cl, sl, 5);
#pragma unroll
            for (int i = 0; i < 32; ++i)
                *(v2f*)(lds + ST * t + 2 * i) = v[i];
#pragma unroll
            for (int u = 0; u < 64; ++u)
                setc(v, u, lds[t + ST * u]);
            butterflies6(v, cl, sl, 11);
            // GrayA: deferred into next odd layer
        }
    }

    // ---- epilogue (B layout, Gray(7) folded): q[g(j)] = psi[j]^2,
    //      j = 64r + t, g(j) = 64*gray6(r) + (gray6(t) ^ 32*(r&1)) ----
#pragma unroll
    for (int i = 0; i < 32; ++i) {
        const int g0 = 64 * gray6(2 * i);
        const int g1 = 64 * (gray6(2 * i) ^ 1);
        lds[g0 + gtl]        = v[i].x * v[i].x;   // bank = gtl&31: 2-way, free
        lds[g1 + (gtl ^ 32)] = v[i].y * v[i].y;
    }

    float acc[NCLASS];
#pragma unroll
    for (int c = 0; c < NCLASS; ++c) acc[c] = 0.f;

#pragma unroll 1
    for (int k = 0; k < 16; ++k) {
        const v4f q4 = *(const v4f*)(lds + 4 * t + 256 * k);   // b128, conflict-free
        const float* wp = W + 4 * t + 256 * k;
#pragma unroll
        for (int c = 0; c < NCLASS; ++c) {
            const v4f w4 = *(const v4f*)(wp + c * DIM);         // dwordx4, L2-resident
            acc[c] += q4.x * w4.x + q4.y * w4.y + q4.z * w4.z + q4.w * w4.w;
        }
    }

#pragma unroll
    for (int c = 0; c < NCLASS; ++c) {
        float a = acc[c];
#pragma unroll
        for (int o = 1; o < 64; o <<= 1) a += __shfl_xor(a, o, 64);
        if (t == 0) out[b * NCLASS + c] = fmaf(a, invn2, bias[c]);
    }
}

extern "C" void kernel_launch(void* const* d_in, const int* in_sizes, int n_in,
                              void* d_out, int out_size, void* d_ws, size_t ws_size,
                              hipStream_t stream) {
    const float* x    = (const float*)d_in[0];
    const float* ang  = (const float*)d_in[1];
    const float* W    = (const float*)d_in[2];
    const float* bias = (const float*)d_in[3];
    float* out = (float*)d_out;
    const int batch = in_sizes[0] / FEAT;   // 2048
    qnn_kernel<<<batch, 64, 0, stream>>>(x, ang, W, bias, out);
}